// Round 1
// baseline (72.228 us; speedup 1.0000x reference)
//
#include <hip/hip_runtime.h>
#include <hip/hip_bf16.h>

typedef __bf16 bf16x8 __attribute__((ext_vector_type(8)));
typedef float f32x4 __attribute__((ext_vector_type(4)));
typedef unsigned short us8 __attribute__((ext_vector_type(8)));
typedef unsigned short us4 __attribute__((ext_vector_type(4)));

#define MFMA16 __builtin_amdgcn_mfma_f32_16x16x32_bf16

__device__ __forceinline__ unsigned short f2bf(float f) {
    unsigned int u = __float_as_uint(f);
    u += 0x7fffu + ((u >> 16) & 1u);   // round-to-nearest-even
    return (unsigned short)(u >> 16);
}

// ---------------- Pass 1: convert x, h to bf16 ----------------
// 8192*512 = 4194304 elems each = 1048576 float4; grid (4096, 2) x 256 exact.
__global__ void cvt_xh_kernel(const float4* __restrict__ x, const float4* __restrict__ h,
                              us4* __restrict__ xb, us4* __restrict__ hb) {
    int i = blockIdx.x * 256 + threadIdx.x;
    const float4* src = blockIdx.y ? h : x;
    us4* dst = blockIdx.y ? hb : xb;
    float4 v = src[i];
    us4 o = { f2bf(v.x), f2bf(v.y), f2bf(v.z), f2bf(v.w) };
    dst[i] = o;
}

// ---------------- Pass 2: convert + transpose weights ----------------
// W[k][n] f32 -> WT[w][n][k] bf16.  grid (8,8,6), 256 threads, 64x64 tile.
__global__ void cvt_w_kernel(const float* __restrict__ W0, const float* __restrict__ W1,
                             const float* __restrict__ W2, const float* __restrict__ W3,
                             const float* __restrict__ W4, const float* __restrict__ W5,
                             unsigned short* __restrict__ WT) {
    __shared__ float tile[64][65];
    const float* W;
    switch (blockIdx.z) {
        case 0: W = W0; break;
        case 1: W = W1; break;
        case 2: W = W2; break;
        case 3: W = W3; break;
        case 4: W = W4; break;
        default: W = W5; break;
    }
    const int k0 = blockIdx.y * 64, n0 = blockIdx.x * 64;
    const int t = threadIdx.x;
    const int fr = t >> 4;          // 0..15
    const int fc = (t & 15) * 4;    // float4 col
#pragma unroll
    for (int p = 0; p < 4; p++) {
        int r = p * 16 + fr;
        float4 v = *(const float4*)&W[(k0 + r) * 512 + n0 + fc];
        tile[r][fc + 0] = v.x; tile[r][fc + 1] = v.y;
        tile[r][fc + 2] = v.z; tile[r][fc + 3] = v.w;
    }
    __syncthreads();
#pragma unroll
    for (int p = 0; p < 2; p++) {
        int item = p * 256 + t;     // 0..511
        int n = item >> 3;          // 0..63
        int kc = (item & 7) * 8;    // 0..56
        us8 o;
#pragma unroll
        for (int j = 0; j < 8; j++) o[j] = f2bf(tile[kc + j][n]);
        *(us8*)&WT[(size_t)blockIdx.z * 262144 + (size_t)(n0 + n) * 512 + k0 + kc] = o;
    }
}

// ---------------- Pass 3: fused 6-GEMM + AUGRU epilogue ----------------
// Tile 64(M) x 64(N), BK=32, 256 threads = 4 waves in 2x2.
// Accumulators per tile: pre_r = x@Wxr + h@Whr ; pre_u = x@Wxu + h@Whu ;
//                        axh  = x@Wxh ; ahh = h@Whh.
__global__ __launch_bounds__(256) void augru_gemm(
    const unsigned short* __restrict__ xb,   // [8192][512] bf16
    const unsigned short* __restrict__ hb,   // [8192][512] bf16
    const unsigned short* __restrict__ WT,   // [6][512(n)][512(k)] bf16
    const float* __restrict__ b_r, const float* __restrict__ b_u, const float* __restrict__ b_h,
    const float* __restrict__ att, const float* __restrict__ h32,
    float* __restrict__ out) {
    // stride 40 elems (80 B): per-row bank shift = 20 -> 2-way conflicts only (free)
    __shared__ unsigned short sx[64][40];
    __shared__ unsigned short sh[64][40];
    __shared__ unsigned short sw[6][64][40];

    const int m0 = blockIdx.y * 64, n0 = blockIdx.x * 64;
    const int t = threadIdx.x;
    const int wave = t >> 6, lane = t & 63;
    const int wr = wave >> 1, wc = wave & 1;      // 2x2 wave grid
    const int lr = lane & 15, lg = lane >> 4;     // fragment row/col + k-group

    f32x4 acc_r[2][2] = {}, acc_u[2][2] = {}, acc_xh[2][2] = {}, acc_hh[2][2] = {};

    // staging assignment: thread t -> row sr (0..63), 16B granule sc
    const int sr = t >> 2;
    const int sc = (t & 3) * 8;
    const unsigned short* xg = xb + (size_t)(m0 + sr) * 512 + sc;
    const unsigned short* hg = hb + (size_t)(m0 + sr) * 512 + sc;
    const unsigned short* wg0 = WT + 0 * 262144 + (size_t)(n0 + sr) * 512 + sc;
    const unsigned short* wg1 = WT + 1 * 262144 + (size_t)(n0 + sr) * 512 + sc;
    const unsigned short* wg2 = WT + 2 * 262144 + (size_t)(n0 + sr) * 512 + sc;
    const unsigned short* wg3 = WT + 3 * 262144 + (size_t)(n0 + sr) * 512 + sc;
    const unsigned short* wg4 = WT + 4 * 262144 + (size_t)(n0 + sr) * 512 + sc;
    const unsigned short* wg5 = WT + 5 * 262144 + (size_t)(n0 + sr) * 512 + sc;

    for (int kb = 0; kb < 512; kb += 32) {
        if (kb) __syncthreads();
        *(us8*)&sx[sr][sc]    = *(const us8*)(xg + kb);
        *(us8*)&sh[sr][sc]    = *(const us8*)(hg + kb);
        *(us8*)&sw[0][sr][sc] = *(const us8*)(wg0 + kb);
        *(us8*)&sw[1][sr][sc] = *(const us8*)(wg1 + kb);
        *(us8*)&sw[2][sr][sc] = *(const us8*)(wg2 + kb);
        *(us8*)&sw[3][sr][sc] = *(const us8*)(wg3 + kb);
        *(us8*)&sw[4][sr][sc] = *(const us8*)(wg4 + kb);
        *(us8*)&sw[5][sr][sc] = *(const us8*)(wg5 + kb);
        __syncthreads();

        const int kk = lg * 8;
        bf16x8 ax[2], ah[2];
        ax[0] = *(const bf16x8*)&sx[wr * 32 + lr][kk];
        ax[1] = *(const bf16x8*)&sx[wr * 32 + 16 + lr][kk];
        ah[0] = *(const bf16x8*)&sh[wr * 32 + lr][kk];
        ah[1] = *(const bf16x8*)&sh[wr * 32 + 16 + lr][kk];
        bf16x8 bw[6][2];
#pragma unroll
        for (int w = 0; w < 6; w++) {
            bw[w][0] = *(const bf16x8*)&sw[w][wc * 32 + lr][kk];
            bw[w][1] = *(const bf16x8*)&sw[w][wc * 32 + 16 + lr][kk];
        }
#pragma unroll
        for (int i = 0; i < 2; i++) {
#pragma unroll
            for (int j = 0; j < 2; j++) {
                acc_r[i][j]  = MFMA16(ax[i], bw[0][j], acc_r[i][j], 0, 0, 0);
                acc_r[i][j]  = MFMA16(ah[i], bw[1][j], acc_r[i][j], 0, 0, 0);
                acc_u[i][j]  = MFMA16(ax[i], bw[2][j], acc_u[i][j], 0, 0, 0);
                acc_u[i][j]  = MFMA16(ah[i], bw[3][j], acc_u[i][j], 0, 0, 0);
                acc_xh[i][j] = MFMA16(ax[i], bw[4][j], acc_xh[i][j], 0, 0, 0);
                acc_hh[i][j] = MFMA16(ah[i], bw[5][j], acc_hh[i][j], 0, 0, 0);
            }
        }
    }

    // epilogue: C/D layout col=lane&15, row=(lane>>4)*4+reg  [m89-verified]
#pragma unroll
    for (int i = 0; i < 2; i++) {
        const int rowb = m0 + wr * 32 + i * 16 + lg * 4;
#pragma unroll
        for (int j = 0; j < 2; j++) {
            const int col = n0 + wc * 32 + j * 16 + lr;
            const float br = b_r[col], bu = b_u[col], bh = b_h[col];
#pragma unroll
            for (int q = 0; q < 4; q++) {
                const int row = rowb + q;
                float r = 1.f / (1.f + __expf(-(acc_r[i][j][q] + br)));
                float u = 1.f / (1.f + __expf(-(acc_u[i][j][q] + bu)));
                float ph = acc_xh[i][j][q] + bh + r * acc_hh[i][j][q];
                ph = fminf(fmaxf(ph, -15.f), 15.f);
                float e = __expf(2.f * ph);
                float cal = (e - 1.f) / (e + 1.f);
                float hv = h32[(size_t)row * 512 + col];
                float ua = att[row] * u;
                out[(size_t)row * 512 + col] = fmaf(ua, cal - hv, hv);
            }
        }
    }
}

extern "C" void kernel_launch(void* const* d_in, const int* in_sizes, int n_in,
                              void* d_out, int out_size, void* d_ws, size_t ws_size,
                              hipStream_t stream) {
    const float* x    = (const float*)d_in[0];
    const float* h    = (const float*)d_in[1];
    const float* att  = (const float*)d_in[2];
    const float* Wx_r = (const float*)d_in[3];
    const float* b_r  = (const float*)d_in[4];
    const float* Wh_r = (const float*)d_in[5];
    const float* Wx_u = (const float*)d_in[6];
    const float* b_u  = (const float*)d_in[7];
    const float* Wh_u = (const float*)d_in[8];
    const float* Wx_h = (const float*)d_in[9];
    const float* b_h  = (const float*)d_in[10];
    const float* Wh_h = (const float*)d_in[11];
    float* out = (float*)d_out;

    unsigned short* xb = (unsigned short*)d_ws;           //  8 MiB
    unsigned short* hb = xb + 8192 * 512;                 //  8 MiB
    unsigned short* WT = hb + 8192 * 512;                 //  3 MiB (6 x 512 x 512)

    cvt_xh_kernel<<<dim3(4096, 2), 256, 0, stream>>>(
        (const float4*)x, (const float4*)h, (us4*)xb, (us4*)hb);
    cvt_w_kernel<<<dim3(8, 8, 6), 256, 0, stream>>>(
        Wx_r, Wh_r, Wx_u, Wh_u, Wx_h, Wh_h, WT);
    augru_gemm<<<dim3(8, 128), 256, 0, stream>>>(
        xb, hb, WT, b_r, b_u, b_h, att, h, out);
}

// Round 2
// 56.234 us; speedup vs baseline: 1.2844x; 1.2844x over previous
//
#include <hip/hip_runtime.h>
#include <hip/hip_bf16.h>

typedef __bf16 bf16x8 __attribute__((ext_vector_type(8)));
typedef float f32x4 __attribute__((ext_vector_type(4)));
typedef unsigned short us8 __attribute__((ext_vector_type(8)));

#define MFMA16 __builtin_amdgcn_mfma_f32_16x16x32_bf16

__device__ __forceinline__ unsigned short f2bf(float f) {
    unsigned int u = __float_as_uint(f);
    u += 0x7fffu + ((u >> 16) & 1u);   // round-to-nearest-even
    return (unsigned short)(u >> 16);
}

__device__ __forceinline__ void gload_lds16(const void* g, void* l) {
    __builtin_amdgcn_global_load_lds(
        (const __attribute__((address_space(1))) unsigned int*)g,
        (__attribute__((address_space(3))) unsigned int*)l, 16, 0, 0);
}

// ============ Pass 1: x,h f32 -> MFMA-fragment-packed bf16 ============
// Packed layout: frag block (mb,kb) = 1024 B; elem (m,k): mb=m>>4, r=m&15,
// kb=k>>5, kk=k&31, lane=(kk>>3)*16+r, byte=((mb*16+kb)*64+lane)*16+(kk&7)*2.
// Thread = one 16B lane-chunk -> output is perfectly linear.
__global__ void cvt_xh_kernel(const float* __restrict__ x, const float* __restrict__ h,
                              unsigned short* __restrict__ XP, unsigned short* __restrict__ HP) {
    int c = blockIdx.x * 256 + threadIdx.x;          // 0 .. 2^20-1
    const float* src = (c >> 19) ? h : x;
    unsigned short* dst = (c >> 19) ? HP : XP;
    int c2 = c & 524287;
    int mb = c2 >> 10, kb = (c2 >> 6) & 15, lane = c2 & 63;
    int r = lane & 15, ko = lane >> 4;
    const float* p = src + (size_t)(mb * 16 + r) * 512 + kb * 32 + ko * 8;
    float4 v0 = *(const float4*)p;
    float4 v1 = *(const float4*)(p + 4);
    us8 o = { f2bf(v0.x), f2bf(v0.y), f2bf(v0.z), f2bf(v0.w),
              f2bf(v1.x), f2bf(v1.y), f2bf(v1.z), f2bf(v1.w) };
    *(us8*)(dst + (size_t)c2 * 8) = o;
}

// ============ Pass 2: weights f32 [k][n] -> fragment-packed bf16 ============
// WP[w][nb][kb][1024B]; elem (n,k): nb=n>>4, cc=n&15, lane=(kk>>3)*16+cc.
__global__ void cvt_w_kernel(const float* __restrict__ W0, const float* __restrict__ W1,
                             const float* __restrict__ W2, const float* __restrict__ W3,
                             const float* __restrict__ W4, const float* __restrict__ W5,
                             unsigned short* __restrict__ WP) {
    int c = blockIdx.x * 256 + threadIdx.x;          // 0 .. 196607
    int w = c >> 15;
    const float* Wsrc;
    switch (w) {
        case 0: Wsrc = W0; break;
        case 1: Wsrc = W1; break;
        case 2: Wsrc = W2; break;
        case 3: Wsrc = W3; break;
        case 4: Wsrc = W4; break;
        default: Wsrc = W5; break;
    }
    int c2 = c & 32767;
    int nb = c2 >> 10, kb = (c2 >> 6) & 15, lane = c2 & 63;
    int cc = lane & 15, ko = lane >> 4;
    int kbase = kb * 32 + ko * 8;
    us8 o;
#pragma unroll
    for (int e = 0; e < 8; ++e)
        o[e] = f2bf(Wsrc[(size_t)(kbase + e) * 512 + nb * 16 + cc]);
    *(us8*)(WP + (size_t)c * 8) = o;
}

// ============ Pass 3: fused 6-GEMM + AUGRU epilogue ============
// Block: 256 rows x 32 cols, 4 waves (64 rows each), BK=32, 16 K-steps.
// A (x,h) direct global->reg (L2-served); B (6 weights) via global_load_lds,
// double-buffered, one barrier per step. All frag reads are base+lane*16.
__global__ __launch_bounds__(256, 2) void augru_mm(
    const unsigned short* __restrict__ XP,   // packed x
    const unsigned short* __restrict__ HP,   // packed h
    const unsigned short* __restrict__ WP,   // packed weights [6][32][16][1KB]
    const float* __restrict__ b_r, const float* __restrict__ b_u, const float* __restrict__ b_h,
    const float* __restrict__ att, const float* __restrict__ h32,
    float* __restrict__ out) {
    __shared__ unsigned char sB[2][12 * 1024];

    const int t = threadIdx.x;
    const int wv = t >> 6, lane = t & 63;
    const size_t laneoff = (size_t)lane * 16;

    // bijective XCD swizzle: each XCD owns 64 consecutive work-ids = 4 m-panels
    const int bid = blockIdx.x;                 // 0..511
    const int W = (bid & 7) * 64 + (bid >> 3);
    const int mblk = W >> 4, nblk = W & 15;
    const int nbase = nblk * 2;
    const int mbase = mblk * 16 + wv * 4;

    f32x4 accR[4][2] = {}, accU[4][2] = {}, accXH[4][2] = {}, accHH[4][2] = {};

    // per-mfrag A base pointers (per-lane addresses)
    const unsigned char* pX[4];
    const unsigned char* pH[4];
#pragma unroll
    for (int mf = 0; mf < 4; ++mf) {
        size_t fb = ((size_t)(mbase + mf) * 16) << 10;
        pX[mf] = (const unsigned char*)XP + fb + laneoff;
        pH[mf] = (const unsigned char*)HP + fb + laneoff;
    }

    // prologue: stage B for kb=0 into buf 0
#pragma unroll
    for (int i = 0; i < 3; ++i) {
        int s = wv * 3 + i;
        int w = s >> 1, nf = s & 1;
        const unsigned char* src = (const unsigned char*)WP +
            ((((size_t)(w * 32 + nbase + nf)) * 16 + 0) << 10) + laneoff;
        gload_lds16(src, &sB[0][s << 10]);
    }
    __syncthreads();

    int buf = 0;
    for (int kb = 0; kb < 16; ++kb) {
        // A loads for this step (oldest in vmcnt queue -> compiler waits only these)
        bf16x8 ax[4], ah[4];
#pragma unroll
        for (int mf = 0; mf < 4; ++mf) {
            ax[mf] = *(const bf16x8*)(pX[mf] + ((size_t)kb << 10));
            ah[mf] = *(const bf16x8*)(pH[mf] + ((size_t)kb << 10));
        }
        // stage next K-step's B (stays in flight through the MFMA block)
        if (kb < 15) {
#pragma unroll
            for (int i = 0; i < 3; ++i) {
                int s = wv * 3 + i;
                int w = s >> 1, nf = s & 1;
                const unsigned char* src = (const unsigned char*)WP +
                    ((((size_t)(w * 32 + nbase + nf)) * 16 + (kb + 1)) << 10) + laneoff;
                gload_lds16(src, &sB[buf ^ 1][s << 10]);
            }
        }
        // B fragment reads: base + lane*16, conflict-free
        bf16x8 bw[6][2];
#pragma unroll
        for (int s = 0; s < 12; ++s)
            bw[s >> 1][s & 1] = *(const bf16x8*)&sB[buf][(s << 10) + laneoff];
        // 48 MFMAs
#pragma unroll
        for (int mf = 0; mf < 4; ++mf) {
#pragma unroll
            for (int nf = 0; nf < 2; ++nf) {
                accR[mf][nf]  = MFMA16(ax[mf], bw[0][nf], accR[mf][nf], 0, 0, 0);
                accR[mf][nf]  = MFMA16(ah[mf], bw[1][nf], accR[mf][nf], 0, 0, 0);
                accU[mf][nf]  = MFMA16(ax[mf], bw[2][nf], accU[mf][nf], 0, 0, 0);
                accU[mf][nf]  = MFMA16(ah[mf], bw[3][nf], accU[mf][nf], 0, 0, 0);
                accXH[mf][nf] = MFMA16(ax[mf], bw[4][nf], accXH[mf][nf], 0, 0, 0);
                accHH[mf][nf] = MFMA16(ah[mf], bw[5][nf], accHH[mf][nf], 0, 0, 0);
            }
        }
        __syncthreads();   // vmcnt(0)+lgkmcnt(0): drains the 3 tiny B-stages; A already consumed
        buf ^= 1;
    }

    // epilogue: C/D layout col=lane&15, row=(lane>>4)*4+reg  [m89-verified]
    const int lr = lane & 15, lg = lane >> 4;
#pragma unroll
    for (int nf = 0; nf < 2; ++nf) {
        const int col = nblk * 32 + nf * 16 + lr;
        const float br = b_r[col], bu = b_u[col], bh = b_h[col];
#pragma unroll
        for (int mf = 0; mf < 4; ++mf) {
            const int rowb = mblk * 256 + wv * 64 + mf * 16 + lg * 4;
#pragma unroll
            for (int q = 0; q < 4; ++q) {
                const int row = rowb + q;
                float r = 1.f / (1.f + __expf(-(accR[mf][nf][q] + br)));
                float u = 1.f / (1.f + __expf(-(accU[mf][nf][q] + bu)));
                float ph = accXH[mf][nf][q] + bh + r * accHH[mf][nf][q];
                ph = fminf(fmaxf(ph, -15.f), 15.f);
                float e = __expf(2.f * ph);
                float cal = (e - 1.f) / (e + 1.f);
                float hv = h32[(size_t)row * 512 + col];
                float ua = att[row] * u;
                out[(size_t)row * 512 + col] = fmaf(ua, cal - hv, hv);
            }
        }
    }
}

extern "C" void kernel_launch(void* const* d_in, const int* in_sizes, int n_in,
                              void* d_out, int out_size, void* d_ws, size_t ws_size,
                              hipStream_t stream) {
    const float* x    = (const float*)d_in[0];
    const float* h    = (const float*)d_in[1];
    const float* att  = (const float*)d_in[2];
    const float* Wx_r = (const float*)d_in[3];
    const float* b_r  = (const float*)d_in[4];
    const float* Wh_r = (const float*)d_in[5];
    const float* Wx_u = (const float*)d_in[6];
    const float* b_u  = (const float*)d_in[7];
    const float* Wh_u = (const float*)d_in[8];
    const float* Wx_h = (const float*)d_in[9];
    const float* b_h  = (const float*)d_in[10];
    const float* Wh_h = (const float*)d_in[11];
    float* out = (float*)d_out;

    unsigned short* XP = (unsigned short*)d_ws;           // 8 MiB
    unsigned short* HP = XP + 8192 * 512;                 // 8 MiB
    unsigned short* WP = HP + 8192 * 512;                 // 3 MiB

    cvt_xh_kernel<<<4096, 256, 0, stream>>>(x, h, XP, HP);
    cvt_w_kernel<<<768, 256, 0, stream>>>(Wx_r, Wh_r, Wx_u, Wh_u, Wx_h, Wh_h, WP);
    augru_mm<<<512, 256, 0, stream>>>(XP, HP, WP, b_r, b_u, b_h, att, h, out);
}

// Round 3
// 48.577 us; speedup vs baseline: 1.4869x; 1.1576x over previous
//
#include <hip/hip_runtime.h>
#include <hip/hip_bf16.h>

typedef __bf16 bf16x8 __attribute__((ext_vector_type(8)));
typedef float f32x4 __attribute__((ext_vector_type(4)));
typedef unsigned short us8 __attribute__((ext_vector_type(8)));

#define MFMA16 __builtin_amdgcn_mfma_f32_16x16x32_bf16

__device__ __forceinline__ unsigned short f2bf(float f) {
    unsigned int u = __float_as_uint(f);
    u += 0x7fffu + ((u >> 16) & 1u);   // round-to-nearest-even
    return (unsigned short)(u >> 16);
}

__device__ __forceinline__ void gload_lds16(const void* g, void* l) {
    __builtin_amdgcn_global_load_lds(
        (const __attribute__((address_space(1))) unsigned int*)g,
        (__attribute__((address_space(3))) unsigned int*)l, 16, 0, 0);
}

// ============ Pass 1 (fused): x,h -> packed bf16 ; weights -> packed bf16 ====
// Packed frag block (mb,kb) = 1024 B; elem (m,k): mb=m>>4, r=m&15, kb=k>>5,
// kk=k&31, lane=(kk>>3)*16+r, byte=((mb*16+kb)*64+lane)*16+(kk&7)*2.
__global__ void cvt_all_kernel(const float* __restrict__ x, const float* __restrict__ h,
                               unsigned short* __restrict__ XP, unsigned short* __restrict__ HP,
                               const float* __restrict__ W0, const float* __restrict__ W1,
                               const float* __restrict__ W2, const float* __restrict__ W3,
                               const float* __restrict__ W4, const float* __restrict__ W5,
                               unsigned short* __restrict__ WP) {
    if (blockIdx.x < 4096) {                         // x,h path
        int c = blockIdx.x * 256 + threadIdx.x;      // 0 .. 2^20-1
        const float* src = (c >> 19) ? h : x;
        unsigned short* dst = (c >> 19) ? HP : XP;
        int c2 = c & 524287;
        int mb = c2 >> 10, kb = (c2 >> 6) & 15, lane = c2 & 63;
        int r = lane & 15, ko = lane >> 4;
        const float* p = src + (size_t)(mb * 16 + r) * 512 + kb * 32 + ko * 8;
        float4 v0 = *(const float4*)p;
        float4 v1 = *(const float4*)(p + 4);
        us8 o = { f2bf(v0.x), f2bf(v0.y), f2bf(v0.z), f2bf(v0.w),
                  f2bf(v1.x), f2bf(v1.y), f2bf(v1.z), f2bf(v1.w) };
        *(us8*)(dst + (size_t)c2 * 8) = o;
    } else {                                          // weights path
        int c = (blockIdx.x - 4096) * 256 + threadIdx.x;   // 0 .. 196607
        int w = c >> 15;
        const float* Wsrc;
        switch (w) {
            case 0: Wsrc = W0; break;
            case 1: Wsrc = W1; break;
            case 2: Wsrc = W2; break;
            case 3: Wsrc = W3; break;
            case 4: Wsrc = W4; break;
            default: Wsrc = W5; break;
        }
        int c2 = c & 32767;
        int nb = c2 >> 10, kb = (c2 >> 6) & 15, lane = c2 & 63;
        int cc = lane & 15, ko = lane >> 4;
        int kbase = kb * 32 + ko * 8;
        us8 o;
#pragma unroll
        for (int e = 0; e < 8; ++e)
            o[e] = f2bf(Wsrc[(size_t)(kbase + e) * 512 + nb * 16 + cc]);
        *(us8*)(WP + (size_t)c * 8) = o;
    }
}

// ============ Pass 2: fused 6-GEMM + AUGRU epilogue ============
// Block: 256 rows x 32 cols, 4 waves (64 rows each), BK=32, 16 K-steps.
// A (x,h): global->reg, REGISTER double-buffered (load kb+1 during kb MFMAs).
// B (6 weights): global_load_lds, LDS double-buffered. One barrier per step.
__global__ __launch_bounds__(256, 2) void augru_mm(
    const unsigned short* __restrict__ XP,
    const unsigned short* __restrict__ HP,
    const unsigned short* __restrict__ WP,   // [6][32(nb)][16(kb)][1KB]
    const float* __restrict__ b_r, const float* __restrict__ b_u, const float* __restrict__ b_h,
    const float* __restrict__ att, const float* __restrict__ h32,
    float* __restrict__ out) {
    __shared__ unsigned char sB[2][12 * 1024];

    const int t = threadIdx.x;
    const int wv = t >> 6, lane = t & 63;
    const size_t laneoff = (size_t)lane * 16;

    // bijective XCD swizzle: each XCD owns 64 consecutive work-ids = 4 m-panels
    const int bid = blockIdx.x;                 // 0..511
    const int W = (bid & 7) * 64 + (bid >> 3);
    const int mblk = W >> 4, nblk = W & 15;
    const int nbase = nblk * 2;
    const int mbase = mblk * 16 + wv * 4;

    f32x4 accR[4][2] = {}, accU[4][2] = {}, accXH[4][2] = {}, accHH[4][2] = {};

    const unsigned char* pX[4];
    const unsigned char* pH[4];
#pragma unroll
    for (int mf = 0; mf < 4; ++mf) {
        size_t fb = ((size_t)(mbase + mf) * 16) << 10;
        pX[mf] = (const unsigned char*)XP + fb + laneoff;
        pH[mf] = (const unsigned char*)HP + fb + laneoff;
    }
    // per-wave B-stage sources (3 stages/wave, s = wv*3+i, w = s>>1, nf = s&1)
    const unsigned char* pW[3];
    unsigned lds_off[3];
#pragma unroll
    for (int i = 0; i < 3; ++i) {
        int s = wv * 3 + i;
        int w = s >> 1, nf = s & 1;
        pW[i] = (const unsigned char*)WP + (((size_t)(w * 32 + nbase + nf) * 16) << 10) + laneoff;
        lds_off[i] = s << 10;
    }

#define STAGE_B(kb1, bufi) \
    { _Pragma("unroll") for (int i = 0; i < 3; ++i) \
        gload_lds16(pW[i] + ((size_t)(kb1) << 10), &sB[bufi][lds_off[i]]); }

#define LOAD_A(kb1, slot) \
    { _Pragma("unroll") for (int mf = 0; mf < 4; ++mf) { \
        ax##slot[mf] = *(const bf16x8*)(pX[mf] + ((size_t)(kb1) << 10)); \
        ah##slot[mf] = *(const bf16x8*)(pH[mf] + ((size_t)(kb1) << 10)); } }

#define DO_MFMA(bufi, slot) \
    { bf16x8 bw[6][2]; \
      _Pragma("unroll") for (int s = 0; s < 12; ++s) \
          bw[s >> 1][s & 1] = *(const bf16x8*)&sB[bufi][(s << 10) + laneoff]; \
      _Pragma("unroll") for (int mf = 0; mf < 4; ++mf) { \
          _Pragma("unroll") for (int nf = 0; nf < 2; ++nf) { \
              accR[mf][nf]  = MFMA16(ax##slot[mf], bw[0][nf], accR[mf][nf], 0, 0, 0); \
              accR[mf][nf]  = MFMA16(ah##slot[mf], bw[1][nf], accR[mf][nf], 0, 0, 0); \
              accU[mf][nf]  = MFMA16(ax##slot[mf], bw[2][nf], accU[mf][nf], 0, 0, 0); \
              accU[mf][nf]  = MFMA16(ah##slot[mf], bw[3][nf], accU[mf][nf], 0, 0, 0); \
              accXH[mf][nf] = MFMA16(ax##slot[mf], bw[4][nf], accXH[mf][nf], 0, 0, 0); \
              accHH[mf][nf] = MFMA16(ah##slot[mf], bw[5][nf], accHH[mf][nf], 0, 0, 0); } } }

    bf16x8 ax0[4], ah0[4], ax1[4], ah1[4];

    // prologue: stage B(0) -> buf0, load A(0) -> slot0
    STAGE_B(0, 0)
    LOAD_A(0, 0)
    __syncthreads();

#pragma unroll 1
    for (int it = 0; it < 8; ++it) {
        const int kb0 = it * 2;       // even step: reads buf0/slot0
        // prefetch kb0+1 (<=15 always)
        STAGE_B(kb0 + 1, 1)
        LOAD_A(kb0 + 1, 1)
        DO_MFMA(0, 0)
        __syncthreads();
        // odd step: reads buf1/slot1
        if (kb0 + 2 < 16) {
            STAGE_B(kb0 + 2, 0)
            LOAD_A(kb0 + 2, 0)
        }
        DO_MFMA(1, 1)
        __syncthreads();
    }

    // epilogue: C/D layout col=lane&15, row=(lane>>4)*4+reg  [m89-verified]
    const int lr = lane & 15, lg = lane >> 4;
#pragma unroll
    for (int nf = 0; nf < 2; ++nf) {
        const int col = nblk * 32 + nf * 16 + lr;
        const float br = b_r[col], bu = b_u[col], bh = b_h[col];
#pragma unroll
        for (int mf = 0; mf < 4; ++mf) {
            const int rowb = mblk * 256 + wv * 64 + mf * 16 + lg * 4;
#pragma unroll
            for (int q = 0; q < 4; ++q) {
                const int row = rowb + q;
                float r = 1.f / (1.f + __expf(-(accR[mf][nf][q] + br)));
                float u = 1.f / (1.f + __expf(-(accU[mf][nf][q] + bu)));
                float ph = accXH[mf][nf][q] + bh + r * accHH[mf][nf][q];
                ph = fminf(fmaxf(ph, -15.f), 15.f);
                float e = __expf(2.f * ph);
                float cal = (e - 1.f) / (e + 1.f);
                float hv = h32[(size_t)row * 512 + col];
                float ua = att[row] * u;
                out[(size_t)row * 512 + col] = fmaf(ua, cal - hv, hv);
            }
        }
    }
#undef STAGE_B
#undef LOAD_A
#undef DO_MFMA
}

extern "C" void kernel_launch(void* const* d_in, const int* in_sizes, int n_in,
                              void* d_out, int out_size, void* d_ws, size_t ws_size,
                              hipStream_t stream) {
    const float* x    = (const float*)d_in[0];
    const float* h    = (const float*)d_in[1];
    const float* att  = (const float*)d_in[2];
    const float* Wx_r = (const float*)d_in[3];
    const float* b_r  = (const float*)d_in[4];
    const float* Wh_r = (const float*)d_in[5];
    const float* Wx_u = (const float*)d_in[6];
    const float* b_u  = (const float*)d_in[7];
    const float* Wh_u = (const float*)d_in[8];
    const float* Wx_h = (const float*)d_in[9];
    const float* b_h  = (const float*)d_in[10];
    const float* Wh_h = (const float*)d_in[11];
    float* out = (float*)d_out;

    unsigned short* XP = (unsigned short*)d_ws;           // 8 MiB
    unsigned short* HP = XP + 8192 * 512;                 // 8 MiB
    unsigned short* WP = HP + 8192 * 512;                 // 3 MiB

    cvt_all_kernel<<<4864, 256, 0, stream>>>(x, h, XP, HP,
        Wx_r, Wh_r, Wx_u, Wh_u, Wx_h, Wh_h, WP);
    augru_mm<<<512, 256, 0, stream>>>(XP, HP, WP, b_r, b_u, b_h, att, h, out);
}

// Round 4
// 46.882 us; speedup vs baseline: 1.5406x; 1.0362x over previous
//
#include <hip/hip_runtime.h>
#include <hip/hip_bf16.h>

typedef __bf16 bf16x8 __attribute__((ext_vector_type(8)));
typedef float f32x4 __attribute__((ext_vector_type(4)));
typedef unsigned short us8 __attribute__((ext_vector_type(8)));

#define MFMA16 __builtin_amdgcn_mfma_f32_16x16x32_bf16

__device__ __forceinline__ unsigned short f2bf(float f) {
    unsigned int u = __float_as_uint(f);
    u += 0x7fffu + ((u >> 16) & 1u);   // round-to-nearest-even
    return (unsigned short)(u >> 16);
}

__device__ __forceinline__ void gload_lds16(const void* g, void* l) {
    __builtin_amdgcn_global_load_lds(
        (const __attribute__((address_space(1))) unsigned int*)g,
        (__attribute__((address_space(3))) unsigned int*)l, 16, 0, 0);
}

// ============ Pass 1 (fused): x,h -> packed bf16 ; weights -> packed bf16 ====
// Packed frag block (mb,kb) = 1024 B; elem (m,k): mb=m>>4, r=m&15, kb=k>>5,
// kk=k&31, lane=(kk>>3)*16+r, byte=((mb*16+kb)*64+lane)*16+(kk&7)*2.
__global__ void cvt_all_kernel(const float* __restrict__ x, const float* __restrict__ h,
                               unsigned short* __restrict__ XP, unsigned short* __restrict__ HP,
                               const float* __restrict__ W0, const float* __restrict__ W1,
                               const float* __restrict__ W2, const float* __restrict__ W3,
                               const float* __restrict__ W4, const float* __restrict__ W5,
                               unsigned short* __restrict__ WP) {
    if (blockIdx.x < 4096) {                         // x,h path
        int c = blockIdx.x * 256 + threadIdx.x;      // 0 .. 2^20-1
        const float* src = (c >> 19) ? h : x;
        unsigned short* dst = (c >> 19) ? HP : XP;
        int c2 = c & 524287;
        int mb = c2 >> 10, kb = (c2 >> 6) & 15, lane = c2 & 63;
        int r = lane & 15, ko = lane >> 4;
        const float* p = src + (size_t)(mb * 16 + r) * 512 + kb * 32 + ko * 8;
        float4 v0 = *(const float4*)p;
        float4 v1 = *(const float4*)(p + 4);
        us8 o = { f2bf(v0.x), f2bf(v0.y), f2bf(v0.z), f2bf(v0.w),
                  f2bf(v1.x), f2bf(v1.y), f2bf(v1.z), f2bf(v1.w) };
        *(us8*)(dst + (size_t)c2 * 8) = o;
    } else {                                          // weights path
        int c = (blockIdx.x - 4096) * 256 + threadIdx.x;   // 0 .. 196607
        int w = c >> 15;
        const float* Wsrc;
        switch (w) {
            case 0: Wsrc = W0; break;
            case 1: Wsrc = W1; break;
            case 2: Wsrc = W2; break;
            case 3: Wsrc = W3; break;
            case 4: Wsrc = W4; break;
            default: Wsrc = W5; break;
        }
        int c2 = c & 32767;
        int nb = c2 >> 10, kb = (c2 >> 6) & 15, lane = c2 & 63;
        int cc = lane & 15, ko = lane >> 4;
        int kbase = kb * 32 + ko * 8;
        us8 o;
#pragma unroll
        for (int e = 0; e < 8; ++e)
            o[e] = f2bf(Wsrc[(size_t)(kbase + e) * 512 + nb * 16 + cc]);
        *(us8*)(WP + (size_t)c * 8) = o;
    }
}

// ============ Pass 2: fused 6-GEMM + AUGRU epilogue ============
// Block: 256 rows x 32 cols, 4 waves (64 rows each), BK=32, 16 K-steps.
// A (x,h): global->reg, register double-buffered.
// B (weights): global_load_lds, LDS double-buffered.
// Barriers are COUNTED: s_waitcnt vmcnt(8) + s_barrier — the 3 B-stages
// (issued oldest) are drained, the 8 A-loads stay in flight across the
// barrier (T4; vmcnt retires in issue order).
__global__ __launch_bounds__(256, 2) void augru_mm(
    const unsigned short* __restrict__ XP,
    const unsigned short* __restrict__ HP,
    const unsigned short* __restrict__ WP,   // [6][32(nb)][16(kb)][1KB]
    const float* __restrict__ b_r, const float* __restrict__ b_u, const float* __restrict__ b_h,
    const float* __restrict__ att, const float* __restrict__ h32,
    float* __restrict__ out) {
    __shared__ unsigned char sB[2][12 * 1024];

    const int t = threadIdx.x;
    const int wv = t >> 6, lane = t & 63;
    const size_t laneoff = (size_t)lane * 16;

    // bijective XCD swizzle: each XCD owns 64 consecutive work-ids = 4 m-panels
    const int bid = blockIdx.x;                 // 0..511
    const int W = (bid & 7) * 64 + (bid >> 3);
    const int mblk = W >> 4, nblk = W & 15;
    const int nbase = nblk * 2;
    const int mbase = mblk * 16 + wv * 4;

    f32x4 accR[4][2] = {}, accU[4][2] = {}, accXH[4][2] = {}, accHH[4][2] = {};

    const unsigned char* pX[4];
    const unsigned char* pH[4];
#pragma unroll
    for (int mf = 0; mf < 4; ++mf) {
        size_t fb = ((size_t)(mbase + mf) * 16) << 10;
        pX[mf] = (const unsigned char*)XP + fb + laneoff;
        pH[mf] = (const unsigned char*)HP + fb + laneoff;
    }
    // per-wave B-stage sources (3 stages/wave, s = wv*3+i, w = s>>1, nf = s&1)
    const unsigned char* pW[3];
    unsigned lds_off[3];
#pragma unroll
    for (int i = 0; i < 3; ++i) {
        int s = wv * 3 + i;
        int w = s >> 1, nf = s & 1;
        pW[i] = (const unsigned char*)WP + (((size_t)(w * 32 + nbase + nf) * 16) << 10) + laneoff;
        lds_off[i] = s << 10;
    }

#define STAGE_B(kb1, bufi) \
    { _Pragma("unroll") for (int i = 0; i < 3; ++i) \
        gload_lds16(pW[i] + ((size_t)(kb1) << 10), &sB[bufi][lds_off[i]]); }

#define LOAD_A(kb1, slot) \
    { _Pragma("unroll") for (int mf = 0; mf < 4; ++mf) { \
        ax##slot[mf] = *(const bf16x8*)(pX[mf] + ((size_t)(kb1) << 10)); \
        ah##slot[mf] = *(const bf16x8*)(pH[mf] + ((size_t)(kb1) << 10)); } }

#define DO_MFMA(bufi, slot) \
    { bf16x8 bw[6][2]; \
      _Pragma("unroll") for (int s = 0; s < 12; ++s) \
          bw[s >> 1][s & 1] = *(const bf16x8*)&sB[bufi][(s << 10) + laneoff]; \
      _Pragma("unroll") for (int mf = 0; mf < 4; ++mf) { \
          _Pragma("unroll") for (int nf = 0; nf < 2; ++nf) { \
              accR[mf][nf]  = MFMA16(ax##slot[mf], bw[0][nf], accR[mf][nf], 0, 0, 0); \
              accR[mf][nf]  = MFMA16(ah##slot[mf], bw[1][nf], accR[mf][nf], 0, 0, 0); \
              accU[mf][nf]  = MFMA16(ax##slot[mf], bw[2][nf], accU[mf][nf], 0, 0, 0); \
              accU[mf][nf]  = MFMA16(ah##slot[mf], bw[3][nf], accU[mf][nf], 0, 0, 0); \
              accXH[mf][nf] = MFMA16(ax##slot[mf], bw[4][nf], accXH[mf][nf], 0, 0, 0); \
              accHH[mf][nf] = MFMA16(ah##slot[mf], bw[5][nf], accHH[mf][nf], 0, 0, 0); } } }

// counted barrier: drain the 3 B-stages (oldest), keep 8 A-loads in flight
#define BARRIER8 asm volatile("s_waitcnt vmcnt(8)\n\ts_barrier" ::: "memory");

    bf16x8 ax0[4], ah0[4], ax1[4], ah1[4];

    // prologue: stage B(0) -> buf0 (oldest), then A(0) -> slot0
    STAGE_B(0, 0)
    LOAD_A(0, 0)
    BARRIER8

#pragma unroll 1
    for (int it = 0; it < 7; ++it) {
        const int kb0 = it * 2;
        // even step: consume buf0/slot0, prefetch kb0+1
        STAGE_B(kb0 + 1, 1)
        LOAD_A(kb0 + 1, 1)
        DO_MFMA(0, 0)
        BARRIER8
        // odd step: consume buf1/slot1, prefetch kb0+2
        STAGE_B(kb0 + 2, 0)
        LOAD_A(kb0 + 2, 0)
        DO_MFMA(1, 1)
        BARRIER8
    }
    // kb = 14: prefetch 15, consume buf0/slot0
    STAGE_B(15, 1)
    LOAD_A(15, 1)
    DO_MFMA(0, 0)
    BARRIER8
    // kb = 15: consume buf1/slot1, no prefetch, no barrier
    DO_MFMA(1, 1)

    // epilogue: C/D layout col=lane&15, row=(lane>>4)*4+reg  [m89-verified]
    const int lr = lane & 15, lg = lane >> 4;
#pragma unroll
    for (int nf = 0; nf < 2; ++nf) {
        const int col = nblk * 32 + nf * 16 + lr;
        const float br = b_r[col], bu = b_u[col], bh = b_h[col];
#pragma unroll
        for (int mf = 0; mf < 4; ++mf) {
            const int rowb = mblk * 256 + wv * 64 + mf * 16 + lg * 4;
#pragma unroll
            for (int q = 0; q < 4; ++q) {
                const int row = rowb + q;
                float r = 1.f / (1.f + __expf(-(accR[mf][nf][q] + br)));
                float u = 1.f / (1.f + __expf(-(accU[mf][nf][q] + bu)));
                float ph = accXH[mf][nf][q] + bh + r * accHH[mf][nf][q];
                ph = fminf(fmaxf(ph, -15.f), 15.f);
                float e = __expf(2.f * ph);
                float cal = (e - 1.f) / (e + 1.f);
                float hv = h32[(size_t)row * 512 + col];
                float ua = att[row] * u;
                out[(size_t)row * 512 + col] = fmaf(ua, cal - hv, hv);
            }
        }
    }
#undef STAGE_B
#undef LOAD_A
#undef DO_MFMA
#undef BARRIER8
}

extern "C" void kernel_launch(void* const* d_in, const int* in_sizes, int n_in,
                              void* d_out, int out_size, void* d_ws, size_t ws_size,
                              hipStream_t stream) {
    const float* x    = (const float*)d_in[0];
    const float* h    = (const float*)d_in[1];
    const float* att  = (const float*)d_in[2];
    const float* Wx_r = (const float*)d_in[3];
    const float* b_r  = (const float*)d_in[4];
    const float* Wh_r = (const float*)d_in[5];
    const float* Wx_u = (const float*)d_in[6];
    const float* b_u  = (const float*)d_in[7];
    const float* Wh_u = (const float*)d_in[8];
    const float* Wx_h = (const float*)d_in[9];
    const float* b_h  = (const float*)d_in[10];
    const float* Wh_h = (const float*)d_in[11];
    float* out = (float*)d_out;

    unsigned short* XP = (unsigned short*)d_ws;           // 8 MiB
    unsigned short* HP = XP + 8192 * 512;                 // 8 MiB
    unsigned short* WP = HP + 8192 * 512;                 // 3 MiB

    cvt_all_kernel<<<4864, 256, 0, stream>>>(x, h, XP, HP,
        Wx_r, Wh_r, Wx_u, Wh_u, Wx_h, Wh_h, WP);
    augru_mm<<<512, 256, 0, stream>>>(XP, HP, WP, b_r, b_u, b_h, att, h, out);
}